// Round 2
// baseline (17554.347 us; speedup 1.0000x reference)
//
#include <hip/hip_runtime.h>
#include <hip/hip_bf16.h>

#define NT 49      // tokens per window
#define HD 32      // head dim
#define NH 16      // heads
#define CDIM 512   // embed dim
#define NOUT (3 * NT * HD)   // 4704 qkv outputs per (window, head)
#define OPT 19               // ceil(4704 / 256)

// One block per (window, head). 256 threads.
__global__ __launch_bounds__(256) void win_attn_kernel(
    const float* __restrict__ x,
    const float* __restrict__ mask,
    const float* __restrict__ qkv_w,
    const float* __restrict__ qkv_b,
    const float* __restrict__ rpb,
    float* __restrict__ out_pre)
{
    const int w   = blockIdx.x >> 4;   // window index (0..1023)
    const int h   = blockIdx.x & 15;   // head index
    const int tid = threadIdx.x;

    __shared__ float xs[NT][128];        // 25088 B: x tile (49 x 128)
    __shared__ float qs[NT][HD];         // q (scaled)
    __shared__ float ks[NT][HD + 1];     // k, padded (phase-2 reads stride rows)
    __shared__ float vs[NT][HD];         // v
    __shared__ float as[NT][NT + 1];     // attention scores, padded

    // ---------------- Phase 1: QKV projection ----------------
    // outputs o in [0, 4704): which = o/1568 (0=q,1=k,2=v), n = (o%1568)/32, j = o%32
    float acc[OPT];
#pragma unroll
    for (int i = 0; i < OPT; ++i) acc[i] = 0.f;

    const float* xw = x + (size_t)w * NT * CDIM;

    for (int c0 = 0; c0 < CDIM; c0 += 128) {
        // stage x[w][:, c0:c0+128]
        for (int i = tid; i < NT * 128; i += 256) {
            int n = i >> 7, cc = i & 127;
            xs[n][cc] = xw[n * CDIM + c0 + cc];
        }
        __syncthreads();

#pragma unroll
        for (int oi = 0; oi < OPT; ++oi) {
            int o = tid + oi * 256;
            if (o < NOUT) {
                int which = o / (NT * HD);
                int rem   = o - which * NT * HD;
                int n = rem >> 5;
                int j = rem & 31;
                const float4* wr4 = (const float4*)(qkv_w + (size_t)(which * CDIM + h * HD + j) * CDIM + c0);
                const float4* xs4 = (const float4*)&xs[n][0];
                float s = 0.f;
#pragma unroll 8
                for (int cc = 0; cc < 32; ++cc) {
                    float4 a = xs4[cc], b = wr4[cc];
                    s += a.x * b.x + a.y * b.y + a.z * b.z + a.w * b.w;
                }
                acc[oi] += s;
            }
        }
        __syncthreads();
    }

    // scatter accumulators to qs/ks/vs (+bias, scale q)
    const float scale = 0.17677669529663687f;  // 32^-0.5
#pragma unroll
    for (int oi = 0; oi < OPT; ++oi) {
        int o = tid + oi * 256;
        if (o < NOUT) {
            int which = o / (NT * HD);
            int rem   = o - which * NT * HD;
            int n = rem >> 5, j = rem & 31;
            float v = acc[oi] + qkv_b[which * CDIM + h * HD + j];
            if (which == 0)      qs[n][j] = v * scale;
            else if (which == 1) ks[n][j] = v;
            else                 vs[n][j] = v;
        }
    }
    __syncthreads();

    // ---------------- Phase 2: scores = q @ k^T + bias + mask ----------------
    for (int o = tid; o < NT * NT; o += 256) {
        int n = o / NT, m = o - n * NT;
        float s = 0.f;
#pragma unroll
        for (int j = 0; j < HD; ++j) s += qs[n][j] * ks[m][j];
        // relative-position bias: idx = ((m/7) - (n/7) + 6) * 13
        int ridx = ((m / 7) - (n / 7) + 6) * 13;
        s += rpb[ridx * NH + h];
        s += mask[((w & 3) * NT + n) * NT + m];
        as[n][m] = s;
    }
    __syncthreads();

    // ---------------- softmax over rows ----------------
    if (tid < NT) {
        float mx = -1e30f;
        for (int m = 0; m < NT; ++m) mx = fmaxf(mx, as[tid][m]);
        float sum = 0.f;
        for (int m = 0; m < NT; ++m) {
            float e = __expf(as[tid][m] - mx);
            as[tid][m] = e;
            sum += e;
        }
        float inv = 1.f / sum;
        for (int m = 0; m < NT; ++m) as[tid][m] *= inv;
    }
    __syncthreads();

    // ---------------- Phase 3: out = attn @ v ----------------
    for (int o = tid; o < NT * HD; o += 256) {
        int n = o >> 5, j = o & 31;
        float s = 0.f;
#pragma unroll
        for (int m = 0; m < NT; ++m) s += as[n][m] * vs[m][j];
        out_pre[(size_t)w * NT * CDIM + n * CDIM + h * HD + j] = s;
    }
}

// In-place output projection on d_out. 16 rows per block.
__global__ __launch_bounds__(256) void proj_kernel(
    float* __restrict__ io,
    const float* __restrict__ proj_w,
    const float* __restrict__ proj_b)
{
    __shared__ float rs[16][CDIM];   // 32 KB
    const int tid = threadIdx.x;
    float* rowbase = io + (size_t)blockIdx.x * 16 * CDIM;

    for (int i = tid; i < 16 * CDIM; i += 256) {
        rs[i >> 9][i & 511] = rowbase[i];
    }
    __syncthreads();

    const int c0 = tid;          // output column 0
    const int c1 = tid + 256;    // output column 1
    float acc0[16], acc1[16];
#pragma unroll
    for (int r = 0; r < 16; ++r) { acc0[r] = 0.f; acc1[r] = 0.f; }

    const float4* w0 = (const float4*)(proj_w + (size_t)c0 * CDIM);
    const float4* w1 = (const float4*)(proj_w + (size_t)c1 * CDIM);
    for (int k4 = 0; k4 < CDIM / 4; ++k4) {
        float4 b0 = w0[k4];
        float4 b1 = w1[k4];
#pragma unroll
        for (int r = 0; r < 16; ++r) {
            float4 a = ((const float4*)rs[r])[k4];
            acc0[r] += a.x * b0.x + a.y * b0.y + a.z * b0.z + a.w * b0.w;
            acc1[r] += a.x * b1.x + a.y * b1.y + a.z * b1.z + a.w * b1.w;
        }
    }
    const float pb0 = proj_b[c0], pb1 = proj_b[c1];
#pragma unroll
    for (int r = 0; r < 16; ++r) {
        rowbase[r * CDIM + c0] = acc0[r] + pb0;
        rowbase[r * CDIM + c1] = acc1[r] + pb1;
    }
}

extern "C" void kernel_launch(void* const* d_in, const int* in_sizes, int n_in,
                              void* d_out, int out_size, void* d_ws, size_t ws_size,
                              hipStream_t stream) {
    const float* x      = (const float*)d_in[0];
    const float* mask   = (const float*)d_in[1];
    const float* qkv_w  = (const float*)d_in[2];
    const float* qkv_b  = (const float*)d_in[3];
    const float* proj_w = (const float*)d_in[4];
    const float* proj_b = (const float*)d_in[5];
    const float* rpb    = (const float*)d_in[6];
    float* out = (float*)d_out;

    // Kernel A: per-(window, head) attention; writes pre-projection activations
    // into d_out (head-major channel layout == transpose(0,2,1,3).reshape).
    win_attn_kernel<<<1024 * NH, 256, 0, stream>>>(x, mask, qkv_w, qkv_b, rpb, out);
    // Kernel B: in-place output projection (each block owns its 16 rows).
    proj_kernel<<<(1024 * NT) / 16, 256, 0, stream>>>(out, proj_w, proj_b);
}

// Round 4
// 697.229 us; speedup vs baseline: 25.1773x; 25.1773x over previous
//
#include <hip/hip_runtime.h>
#include <hip/hip_bf16.h>
#include <stdint.h>

#define NT 49
#define HD 32
#define NH 16
#define CDIM 512
#define MROWS (1024 * 49)        // 50176 token rows
#define NQKV (3 * CDIM)          // 1536

typedef __attribute__((ext_vector_type(8))) __bf16 bf16x8;
typedef __attribute__((ext_vector_type(4))) float f32x4;

__device__ inline ushort f2bf(float f) {
    union { float f; uint32_t u; } c; c.f = f;
    return (ushort)((c.u + 0x7FFFu + ((c.u >> 16) & 1u)) >> 16);
}
__device__ inline float bf2f(ushort b) {
    union { uint32_t u; float f; } c; c.u = ((uint32_t)b) << 16;
    return c.f;
}
// async 16B/lane global->LDS (lds dest = wave-uniform base + lane*16)
__device__ inline void gl_lds16(const ushort* g, ushort* l) {
    __builtin_amdgcn_global_load_lds(
        (const __attribute__((address_space(1))) uint32_t*)g,
        (__attribute__((address_space(3))) uint32_t*)l, 16, 0, 0);
}

// ---- K0: weight fp32 -> bf16 conversion ----
__global__ __launch_bounds__(256) void convert_weights(
    const float* __restrict__ qkv_w, const float* __restrict__ proj_w,
    ushort* __restrict__ Wq, ushort* __restrict__ Wp)
{
    int idx = blockIdx.x * 256 + threadIdx.x;        // grid covers 1048576 exactly
    const int n1 = NQKV * CDIM;                      // 786432
    if (idx < n1) Wq[idx] = f2bf(qkv_w[idx]);
    else          Wp[idx - n1] = f2bf(proj_w[idx - n1]);
}

// ---- K1: QKV GEMM: C[M,1536] = X[M,512] @ Wq^T, +bias, q*scale, bf16 out ----
__global__ __launch_bounds__(256) void qkv_gemm(
    const float* __restrict__ x, const ushort* __restrict__ Wq,
    const float* __restrict__ qkv_b, ushort* __restrict__ QKV)
{
    __shared__ ushort As[128 * 32];
    __shared__ ushort Bs[128 * 32];
    const int tid  = threadIdx.x;
    const int lane = tid & 63, wv = tid >> 6;
    const int n0 = blockIdx.x * 128, m0 = blockIdx.y * 128;
    const int wr = wv >> 1, wc = wv & 1;
    const int lr = lane & 15, lk = lane >> 4;

    f32x4 acc[4][4];
#pragma unroll
    for (int a = 0; a < 4; ++a)
#pragma unroll
        for (int b = 0; b < 4; ++b) acc[a][b] = (f32x4)0.f;

    // A staging: thread -> (row, 16-col half)
    const int ar = tid >> 1, ah = tid & 1;
    const float* ag = x + (size_t)(m0 + ar) * CDIM + ah * 16;
    uint32_t* aw = (uint32_t*)As + ar * 16 + ah * 8;
    // B staging lanes
    const int b_r = lane >> 2, b_c = lane & 3;

    for (int kt = 0; kt < CDIM; kt += 32) {
        if (kt) __syncthreads();
        // B: async global->LDS, 2 groups of 16 rows per wave
#pragma unroll
        for (int gi = 0; gi < 2; ++gi) {
            int grp = wv * 2 + gi;
            const ushort* src = Wq + (size_t)(n0 + grp * 16 + b_r) * CDIM + kt + b_c * 8;
            gl_lds16(src, Bs + grp * 512);
        }
        // A: 16 fp32 -> 16 bf16 -> LDS
        float4 f0 = *(const float4*)(ag + kt + 0);
        float4 f1 = *(const float4*)(ag + kt + 4);
        float4 f2 = *(const float4*)(ag + kt + 8);
        float4 f3 = *(const float4*)(ag + kt + 12);
        uint32_t u0 = (uint32_t)f2bf(f0.x) | ((uint32_t)f2bf(f0.y) << 16);
        uint32_t u1 = (uint32_t)f2bf(f0.z) | ((uint32_t)f2bf(f0.w) << 16);
        uint32_t u2 = (uint32_t)f2bf(f1.x) | ((uint32_t)f2bf(f1.y) << 16);
        uint32_t u3 = (uint32_t)f2bf(f1.z) | ((uint32_t)f2bf(f1.w) << 16);
        uint32_t u4 = (uint32_t)f2bf(f2.x) | ((uint32_t)f2bf(f2.y) << 16);
        uint32_t u5 = (uint32_t)f2bf(f2.z) | ((uint32_t)f2bf(f2.w) << 16);
        uint32_t u6 = (uint32_t)f2bf(f3.x) | ((uint32_t)f2bf(f3.y) << 16);
        uint32_t u7 = (uint32_t)f2bf(f3.z) | ((uint32_t)f2bf(f3.w) << 16);
        *(uint4*)(aw + 0) = make_uint4(u0, u1, u2, u3);
        *(uint4*)(aw + 4) = make_uint4(u4, u5, u6, u7);
        __syncthreads();   // drains vmcnt (gl_lds) + lgkm (ds_write)

        bf16x8 af[4], bq[4];
#pragma unroll
        for (int mr = 0; mr < 4; ++mr)
            af[mr] = *(const bf16x8*)(As + (wr * 64 + mr * 16 + lr) * 32 + lk * 8);
#pragma unroll
        for (int nc = 0; nc < 4; ++nc)
            bq[nc] = *(const bf16x8*)(Bs + (wc * 64 + nc * 16 + lr) * 32 + lk * 8);
#pragma unroll
        for (int mr = 0; mr < 4; ++mr)
#pragma unroll
            for (int nc = 0; nc < 4; ++nc)
                acc[mr][nc] = __builtin_amdgcn_mfma_f32_16x16x32_bf16(
                    af[mr], bq[nc], acc[mr][nc], 0, 0, 0);
    }

    const float scale = (n0 < CDIM) ? 0.17677669529663687f : 1.0f; // 128-tile uniform
#pragma unroll
    for (int nc = 0; nc < 4; ++nc) {
        int col = n0 + wc * 64 + nc * 16 + lr;
        float bias = qkv_b[col];
#pragma unroll
        for (int mr = 0; mr < 4; ++mr)
#pragma unroll
            for (int r = 0; r < 4; ++r) {
                int row = m0 + wr * 64 + mr * 16 + lk * 4 + r;
                QKV[(size_t)row * NQKV + col] = f2bf((acc[mr][nc][r] + bias) * scale);
            }
    }
}

// ---- K2: per-(window,head) attention, bf16 in/out ----
__global__ __launch_bounds__(256) void attn_kernel(
    const ushort* __restrict__ QKV, const float* __restrict__ mask,
    const float* __restrict__ rpb, ushort* __restrict__ AT)
{
    const int w = blockIdx.x >> 4, h = blockIdx.x & 15;
    const int tid = threadIdx.x;
    __shared__ float qs[NT][HD];
    __shared__ float ks[NT][HD + 1];
    __shared__ float vs[NT][HD];
    __shared__ float as_[NT][NT + 1];

    const ushort* base = QKV + (size_t)w * NT * NQKV + h * HD;
    for (int i = tid; i < 3 * NT * HD; i += 256) {
        int which = i / (NT * HD);
        int rem = i - which * NT * HD;
        int n = rem >> 5, j = rem & 31;
        float v = bf2f(base[(size_t)n * NQKV + which * CDIM + j]);
        if (which == 0) qs[n][j] = v;          // q pre-scaled in K1
        else if (which == 1) ks[n][j] = v;
        else vs[n][j] = v;
    }
    __syncthreads();

    const float* mk = mask + (size_t)(w & 3) * NT * NT;
    for (int o = tid; o < NT * NT; o += 256) {
        int n = o / NT, m = o - n * NT;
        float s = 0.f;
#pragma unroll
        for (int j = 0; j < HD; ++j) s += qs[n][j] * ks[m][j];
        s += rpb[((m / 7) - (n / 7) + 6) * 13 * NH + h];
        s += mk[n * NT + m];
        as_[n][m] = s;
    }
    __syncthreads();

    if (tid < NT) {
        float mx = -1e30f;
        for (int m = 0; m < NT; ++m) mx = fmaxf(mx, as_[tid][m]);
        float sum = 0.f;
        for (int m = 0; m < NT; ++m) { float e = __expf(as_[tid][m] - mx); as_[tid][m] = e; sum += e; }
        float inv = 1.f / sum;
        for (int m = 0; m < NT; ++m) as_[tid][m] *= inv;
    }
    __syncthreads();

    ushort* ob = AT + (size_t)w * NT * CDIM + h * HD;
    for (int o = tid; o < NT * HD; o += 256) {
        int n = o >> 5, j = o & 31;
        float s = 0.f;
#pragma unroll
        for (int m = 0; m < NT; ++m) s += as_[n][m] * vs[m][j];
        ob[(size_t)n * CDIM + j] = f2bf(s);
    }
}

// ---- K3: proj GEMM: out[M,512] = AT[M,512] @ Wp^T + b, fp32 out ----
__global__ __launch_bounds__(256) void proj_gemm(
    const ushort* __restrict__ AT, const ushort* __restrict__ Wp,
    const float* __restrict__ proj_b, float* __restrict__ out)
{
    __shared__ ushort As[128 * 32];
    __shared__ ushort Bs[128 * 32];
    const int tid  = threadIdx.x;
    const int lane = tid & 63, wv = tid >> 6;
    const int n0 = blockIdx.x * 128, m0 = blockIdx.y * 128;
    const int wr = wv >> 1, wc = wv & 1;
    const int lr = lane & 15, lk = lane >> 4;

    f32x4 acc[4][4];
#pragma unroll
    for (int a = 0; a < 4; ++a)
#pragma unroll
        for (int b = 0; b < 4; ++b) acc[a][b] = (f32x4)0.f;

    const int b_r = lane >> 2, b_c = lane & 3;

    for (int kt = 0; kt < CDIM; kt += 32) {
        if (kt) __syncthreads();
#pragma unroll
        for (int gi = 0; gi < 2; ++gi) {
            int grp = wv * 2 + gi;
            gl_lds16(AT + (size_t)(m0 + grp * 16 + b_r) * CDIM + kt + b_c * 8, As + grp * 512);
            gl_lds16(Wp + (size_t)(n0 + grp * 16 + b_r) * CDIM + kt + b_c * 8, Bs + grp * 512);
        }
        __syncthreads();

        bf16x8 af[4], bq[4];
#pragma unroll
        for (int mr = 0; mr < 4; ++mr)
            af[mr] = *(const bf16x8*)(As + (wr * 64 + mr * 16 + lr) * 32 + lk * 8);
#pragma unroll
        for (int nc = 0; nc < 4; ++nc)
            bq[nc] = *(const bf16x8*)(Bs + (wc * 64 + nc * 16 + lr) * 32 + lk * 8);
#pragma unroll
        for (int mr = 0; mr < 4; ++mr)
#pragma unroll
            for (int nc = 0; nc < 4; ++nc)
                acc[mr][nc] = __builtin_amdgcn_mfma_f32_16x16x32_bf16(
                    af[mr], bq[nc], acc[mr][nc], 0, 0, 0);
    }

#pragma unroll
    for (int nc = 0; nc < 4; ++nc) {
        int col = n0 + wc * 64 + nc * 16 + lr;
        float bias = proj_b[col];
#pragma unroll
        for (int mr = 0; mr < 4; ++mr)
#pragma unroll
            for (int r = 0; r < 4; ++r) {
                int row = m0 + wr * 64 + mr * 16 + lk * 4 + r;
                out[(size_t)row * CDIM + col] = acc[mr][nc][r] + bias;
            }
    }
}

extern "C" void kernel_launch(void* const* d_in, const int* in_sizes, int n_in,
                              void* d_out, int out_size, void* d_ws, size_t ws_size,
                              hipStream_t stream) {
    const float* x      = (const float*)d_in[0];
    const float* mask   = (const float*)d_in[1];
    const float* qkv_w  = (const float*)d_in[2];
    const float* qkv_b  = (const float*)d_in[3];
    const float* proj_w = (const float*)d_in[4];
    const float* proj_b = (const float*)d_in[5];
    const float* rpb    = (const float*)d_in[6];
    float* out = (float*)d_out;

    // ws layout (bf16/ushort elements)
    ushort* Wq  = (ushort*)d_ws;                       // 1536*512
    ushort* Wp  = Wq + (size_t)NQKV * CDIM;            // 512*512
    ushort* QKV = Wp + (size_t)CDIM * CDIM;            // 50176*1536
    ushort* AT  = QKV + (size_t)MROWS * NQKV;          // 50176*512
    size_t need = ((size_t)NQKV * CDIM + (size_t)CDIM * CDIM +
                   (size_t)MROWS * NQKV + (size_t)MROWS * CDIM) * sizeof(ushort);
    if (ws_size < need) return;  // cannot run without scratch (fails loudly, no corruption)

    convert_weights<<<4096, 256, 0, stream>>>(qkv_w, proj_w, Wq, Wp);
    qkv_gemm<<<dim3(12, 392), 256, 0, stream>>>(x, Wq, qkv_b, QKV);
    attn_kernel<<<1024 * NH, 256, 0, stream>>>(QKV, mask, rpb, AT);
    proj_gemm<<<dim3(4, 392), 256, 0, stream>>>(AT, Wp, proj_b, out);
}

// Round 5
// 535.041 us; speedup vs baseline: 32.8093x; 1.3031x over previous
//
#include <hip/hip_runtime.h>
#include <hip/hip_bf16.h>
#include <stdint.h>

#define NT 49
#define HD 32
#define NH 16
#define CDIM 512
#define MROWS (1024 * 49)        // 50176 token rows
#define NQKV (3 * CDIM)          // 1536

typedef __attribute__((ext_vector_type(8))) __bf16 bf16x8;
typedef __attribute__((ext_vector_type(4))) float f32x4;

__device__ inline ushort f2bf(float f) {
    union { float f; uint32_t u; } c; c.f = f;
    return (ushort)((c.u + 0x7FFFu + ((c.u >> 16) & 1u)) >> 16);
}
__device__ inline float bf2f(ushort b) {
    union { uint32_t u; float f; } c; c.u = ((uint32_t)b) << 16;
    return c.f;
}
// async 16B/lane global->LDS (lds dest = wave-uniform base + lane*16)
__device__ inline void gl_lds16(const ushort* g, ushort* l) {
    __builtin_amdgcn_global_load_lds(
        (const __attribute__((address_space(1))) uint32_t*)g,
        (__attribute__((address_space(3))) uint32_t*)l, 16, 0, 0);
}

// ---- K0: weight fp32 -> bf16 conversion ----
__global__ __launch_bounds__(256) void convert_weights(
    const float* __restrict__ qkv_w, const float* __restrict__ proj_w,
    ushort* __restrict__ Wq, ushort* __restrict__ Wp)
{
    int idx = blockIdx.x * 256 + threadIdx.x;
    const int n1 = NQKV * CDIM;
    if (idx < n1) Wq[idx] = f2bf(qkv_w[idx]);
    else          Wp[idx - n1] = f2bf(proj_w[idx - n1]);
}

// ---- K1: QKV GEMM: C[M,1536] = X[M,512] @ Wq^T, +bias, q*scale, bf16 out ----
__global__ __launch_bounds__(256) void qkv_gemm(
    const float* __restrict__ x, const ushort* __restrict__ Wq,
    const float* __restrict__ qkv_b, ushort* __restrict__ QKV)
{
    __shared__ ushort As[128 * 32];
    __shared__ ushort Bs[128 * 32];
    const int tid  = threadIdx.x;
    const int lane = tid & 63, wv = tid >> 6;
    const int n0 = blockIdx.x * 128, m0 = blockIdx.y * 128;
    const int wr = wv >> 1, wc = wv & 1;
    const int lr = lane & 15, lk = lane >> 4;

    f32x4 acc[4][4];
#pragma unroll
    for (int a = 0; a < 4; ++a)
#pragma unroll
        for (int b = 0; b < 4; ++b) acc[a][b] = (f32x4)0.f;

    const int ar = tid >> 1, ah = tid & 1;
    const float* ag = x + (size_t)(m0 + ar) * CDIM + ah * 16;
    uint32_t* aw = (uint32_t*)As + ar * 16 + ah * 8;
    const int b_r = lane >> 2, b_c = lane & 3;

    for (int kt = 0; kt < CDIM; kt += 32) {
        if (kt) __syncthreads();
#pragma unroll
        for (int gi = 0; gi < 2; ++gi) {
            int grp = wv * 2 + gi;
            const ushort* src = Wq + (size_t)(n0 + grp * 16 + b_r) * CDIM + kt + b_c * 8;
            gl_lds16(src, Bs + grp * 512);
        }
        float4 f0 = *(const float4*)(ag + kt + 0);
        float4 f1 = *(const float4*)(ag + kt + 4);
        float4 f2 = *(const float4*)(ag + kt + 8);
        float4 f3 = *(const float4*)(ag + kt + 12);
        uint32_t u0 = (uint32_t)f2bf(f0.x) | ((uint32_t)f2bf(f0.y) << 16);
        uint32_t u1 = (uint32_t)f2bf(f0.z) | ((uint32_t)f2bf(f0.w) << 16);
        uint32_t u2 = (uint32_t)f2bf(f1.x) | ((uint32_t)f2bf(f1.y) << 16);
        uint32_t u3 = (uint32_t)f2bf(f1.z) | ((uint32_t)f2bf(f1.w) << 16);
        uint32_t u4 = (uint32_t)f2bf(f2.x) | ((uint32_t)f2bf(f2.y) << 16);
        uint32_t u5 = (uint32_t)f2bf(f2.z) | ((uint32_t)f2bf(f2.w) << 16);
        uint32_t u6 = (uint32_t)f2bf(f3.x) | ((uint32_t)f2bf(f3.y) << 16);
        uint32_t u7 = (uint32_t)f2bf(f3.z) | ((uint32_t)f2bf(f3.w) << 16);
        *(uint4*)(aw + 0) = make_uint4(u0, u1, u2, u3);
        *(uint4*)(aw + 4) = make_uint4(u4, u5, u6, u7);
        __syncthreads();

        bf16x8 af[4], bq[4];
#pragma unroll
        for (int mr = 0; mr < 4; ++mr)
            af[mr] = *(const bf16x8*)(As + (wr * 64 + mr * 16 + lr) * 32 + lk * 8);
#pragma unroll
        for (int nc = 0; nc < 4; ++nc)
            bq[nc] = *(const bf16x8*)(Bs + (wc * 64 + nc * 16 + lr) * 32 + lk * 8);
#pragma unroll
        for (int mr = 0; mr < 4; ++mr)
#pragma unroll
            for (int nc = 0; nc < 4; ++nc)
                acc[mr][nc] = __builtin_amdgcn_mfma_f32_16x16x32_bf16(
                    af[mr], bq[nc], acc[mr][nc], 0, 0, 0);
    }

    const float scale = (n0 < CDIM) ? 0.17677669529663687f : 1.0f;
#pragma unroll
    for (int nc = 0; nc < 4; ++nc) {
        int col = n0 + wc * 64 + nc * 16 + lr;
        float bias = qkv_b[col];
#pragma unroll
        for (int mr = 0; mr < 4; ++mr)
#pragma unroll
            for (int r = 0; r < 4; ++r) {
                int row = m0 + wr * 64 + mr * 16 + lk * 4 + r;
                QKV[(size_t)row * NQKV + col] = f2bf((acc[mr][nc][r] + bias) * scale);
            }
    }
}

// ---- K2: MFMA attention. One block = one window x 4 heads; one wave = one head ----
__global__ __launch_bounds__(256) void attn_mfma(
    const ushort* __restrict__ QKV, const float* __restrict__ mask,
    const float* __restrict__ rpb, ushort* __restrict__ AT)
{
    const int w    = blockIdx.x >> 2;
    const int wv   = threadIdx.x >> 6;
    const int h    = ((blockIdx.x & 3) << 2) + wv;
    const int lane = threadIdx.x & 63;
    const int lr   = lane & 15, g = lane >> 4;

    __shared__ float  ms[NT][52];        // mask tile (2-way max on stride)
    __shared__ float  rbuf[4][16];       // per-wave rpb (13 used)
    __shared__ ushort vt[4][32][70];     // V^T per wave: [j][key]
    __shared__ ushort ps[4][64][70];     // P per wave (reused as O staging)

    // stage mask for this window (shared by all 4 waves)
    const float* mk = mask + (size_t)(w & 3) * NT * NT;
    for (int i = threadIdx.x; i < NT * NT; i += 256)
        ms[i / NT][i % NT] = mk[i];
    if (lane < 13) rbuf[wv][lane] = rpb[lane * 13 * NH + h];
    __syncthreads();

    const ushort* base = QKV + (size_t)w * NT * NQKV + h * HD;

    union { bf16x8 v; uint4 u; } zf; zf.u = make_uint4(0, 0, 0, 0);

    // Q fragments (A: row-major [M][K]); K fragments (B: row-major [N][K]).
    // lane holds 16B at (row/col = tile*16+lr, k = g*8..g*8+7); one head row = 64B line.
    bf16x8 aq[4], bk[4];
#pragma unroll
    for (int mt = 0; mt < 4; ++mt) {
        int row = mt * 16 + lr;
        aq[mt] = (row < NT) ? *(const bf16x8*)(base + (size_t)row * NQKV + g * 8) : zf.v;
    }
#pragma unroll
    for (int nt = 0; nt < 4; ++nt) {
        int col = nt * 16 + lr;
        bk[nt] = (col < NT) ? *(const bf16x8*)(base + CDIM + (size_t)col * NQKV + g * 8) : zf.v;
    }

    // stage V transposed: vt[j][n] = V[n][j] (coalesced global read, scattered LDS write)
    for (int i = lane; i < NT * HD; i += 64) {
        int n = i >> 5, j = i & 31;
        vt[wv][j][n] = base[2 * CDIM + (size_t)n * NQKV + j];
    }
    for (int i = lane; i < HD * 15; i += 64) {       // zero keys 49..63
        int j = i / 15, n = NT + i % 15;
        vt[wv][j][n] = 0;
    }

    // QK^T: S[n][m], n = mt*16+g*4+r, m = nt*16+lr
    f32x4 s[4][4];
#pragma unroll
    for (int a = 0; a < 4; ++a)
#pragma unroll
        for (int b = 0; b < 4; ++b) s[a][b] = (f32x4)0.f;
#pragma unroll
    for (int mt = 0; mt < 4; ++mt)
#pragma unroll
        for (int nt = 0; nt < 4; ++nt)
            s[mt][nt] = __builtin_amdgcn_mfma_f32_16x16x32_bf16(aq[mt], bk[nt], s[mt][nt], 0, 0, 0);

    // bias + mask + wave-parallel softmax; write P (bf16) to ps
#pragma unroll
    for (int mt = 0; mt < 4; ++mt) {
#pragma unroll
        for (int r = 0; r < 4; ++r) {
            int row  = mt * 16 + g * 4 + r;
            int rowc = (row < NT) ? row : (NT - 1);
            int nh   = rowc / 7;
            float vals[4];
            float mx = -1e30f;
#pragma unroll
            for (int nt = 0; nt < 4; ++nt) {
                int col = nt * 16 + lr;
                float v = -1e30f;
                if (col < NT)
                    v = s[mt][nt][r] + ms[rowc][col] + rbuf[wv][col / 7 - nh + 6];
                vals[nt] = v;
                mx = fmaxf(mx, v);
            }
            mx = fmaxf(mx, __shfl_xor(mx, 1, 64));
            mx = fmaxf(mx, __shfl_xor(mx, 2, 64));
            mx = fmaxf(mx, __shfl_xor(mx, 4, 64));
            mx = fmaxf(mx, __shfl_xor(mx, 8, 64));
            float sum = 0.f;
#pragma unroll
            for (int nt = 0; nt < 4; ++nt) {
                float p = (vals[nt] > -1e29f) ? __expf(vals[nt] - mx) : 0.f;
                vals[nt] = p;
                sum += p;
            }
            sum += __shfl_xor(sum, 1, 64);
            sum += __shfl_xor(sum, 2, 64);
            sum += __shfl_xor(sum, 4, 64);
            sum += __shfl_xor(sum, 8, 64);
            float inv = 1.f / sum;
#pragma unroll
            for (int nt = 0; nt < 4; ++nt)
                ps[wv][row][nt * 16 + lr] = f2bf(vals[nt] * inv);  // cols>=49 get 0
        }
    }

    // PV: O = P[64x64] @ V[64x32].  A from ps (row-major [M][K]); B from vt ([N][K]).
    bf16x8 ap[4][2], bv[2][2];
#pragma unroll
    for (int mt = 0; mt < 4; ++mt)
#pragma unroll
        for (int ks = 0; ks < 2; ++ks)
            ap[mt][ks] = *(const bf16x8*)&ps[wv][mt * 16 + lr][ks * 32 + g * 8];
#pragma unroll
    for (int nt = 0; nt < 2; ++nt)
#pragma unroll
        for (int ks = 0; ks < 2; ++ks)
            bv[nt][ks] = *(const bf16x8*)&vt[wv][nt * 16 + lr][ks * 32 + g * 8];

    f32x4 o[4][2];
#pragma unroll
    for (int a = 0; a < 4; ++a)
#pragma unroll
        for (int b = 0; b < 2; ++b) o[a][b] = (f32x4)0.f;
#pragma unroll
    for (int mt = 0; mt < 4; ++mt)
#pragma unroll
        for (int nt = 0; nt < 2; ++nt)
#pragma unroll
            for (int ks = 0; ks < 2; ++ks)
                o[mt][nt] = __builtin_amdgcn_mfma_f32_16x16x32_bf16(ap[mt][ks], bv[nt][ks], o[mt][nt], 0, 0, 0);

    // stage O (bf16) into ps rows, then coalesced copy out
#pragma unroll
    for (int mt = 0; mt < 4; ++mt)
#pragma unroll
        for (int nt = 0; nt < 2; ++nt)
#pragma unroll
            for (int r = 0; r < 4; ++r) {
                int row = mt * 16 + g * 4 + r;
                ps[wv][row][nt * 16 + lr] = f2bf(o[mt][nt][r]);
            }

    ushort* ob = AT + (size_t)w * NT * CDIM + h * HD;
    for (int i = lane; i < NT * 16; i += 64) {
        int row = i >> 4, cd = i & 15;
        uint32_t val = *(const uint32_t*)&ps[wv][row][cd * 2];
        *(uint32_t*)(ob + (size_t)row * CDIM + cd * 2) = val;
    }
}

// ---- K3: proj GEMM: out[M,512] = AT[M,512] @ Wp^T + b, fp32 out ----
__global__ __launch_bounds__(256) void proj_gemm(
    const ushort* __restrict__ AT, const ushort* __restrict__ Wp,
    const float* __restrict__ proj_b, float* __restrict__ out)
{
    __shared__ ushort As[128 * 32];
    __shared__ ushort Bs[128 * 32];
    const int tid  = threadIdx.x;
    const int lane = tid & 63, wv = tid >> 6;
    const int n0 = blockIdx.x * 128, m0 = blockIdx.y * 128;
    const int wr = wv >> 1, wc = wv & 1;
    const int lr = lane & 15, lk = lane >> 4;

    f32x4 acc[4][4];
#pragma unroll
    for (int a = 0; a < 4; ++a)
#pragma unroll
        for (int b = 0; b < 4; ++b) acc[a][b] = (f32x4)0.f;

    const int b_r = lane >> 2, b_c = lane & 3;

    for (int kt = 0; kt < CDIM; kt += 32) {
        if (kt) __syncthreads();
#pragma unroll
        for (int gi = 0; gi < 2; ++gi) {
            int grp = wv * 2 + gi;
            gl_lds16(AT + (size_t)(m0 + grp * 16 + b_r) * CDIM + kt + b_c * 8, As + grp * 512);
            gl_lds16(Wp + (size_t)(n0 + grp * 16 + b_r) * CDIM + kt + b_c * 8, Bs + grp * 512);
        }
        __syncthreads();

        bf16x8 af[4], bq[4];
#pragma unroll
        for (int mr = 0; mr < 4; ++mr)
            af[mr] = *(const bf16x8*)(As + (wr * 64 + mr * 16 + lr) * 32 + lk * 8);
#pragma unroll
        for (int nc = 0; nc < 4; ++nc)
            bq[nc] = *(const bf16x8*)(Bs + (wc * 64 + nc * 16 + lr) * 32 + lk * 8);
#pragma unroll
        for (int mr = 0; mr < 4; ++mr)
#pragma unroll
            for (int nc = 0; nc < 4; ++nc)
                acc[mr][nc] = __builtin_amdgcn_mfma_f32_16x16x32_bf16(
                    af[mr], bq[nc], acc[mr][nc], 0, 0, 0);
    }

#pragma unroll
    for (int nc = 0; nc < 4; ++nc) {
        int col = n0 + wc * 64 + nc * 16 + lr;
        float bias = proj_b[col];
#pragma unroll
        for (int mr = 0; mr < 4; ++mr)
#pragma unroll
            for (int r = 0; r < 4; ++r) {
                int row = m0 + wr * 64 + mr * 16 + lk * 4 + r;
                out[(size_t)row * CDIM + col] = acc[mr][nc][r] + bias;
            }
    }
}

extern "C" void kernel_launch(void* const* d_in, const int* in_sizes, int n_in,
                              void* d_out, int out_size, void* d_ws, size_t ws_size,
                              hipStream_t stream) {
    const float* x      = (const float*)d_in[0];
    const float* mask   = (const float*)d_in[1];
    const float* qkv_w  = (const float*)d_in[2];
    const float* qkv_b  = (const float*)d_in[3];
    const float* proj_w = (const float*)d_in[4];
    const float* proj_b = (const float*)d_in[5];
    const float* rpb    = (const float*)d_in[6];
    float* out = (float*)d_out;

    ushort* Wq  = (ushort*)d_ws;                       // 1536*512
    ushort* Wp  = Wq + (size_t)NQKV * CDIM;            // 512*512
    ushort* QKV = Wp + (size_t)CDIM * CDIM;            // 50176*1536
    ushort* AT  = QKV + (size_t)MROWS * NQKV;          // 50176*512
    size_t need = ((size_t)NQKV * CDIM + (size_t)CDIM * CDIM +
                   (size_t)MROWS * NQKV + (size_t)MROWS * CDIM) * sizeof(ushort);
    if (ws_size < need) return;

    convert_weights<<<4096, 256, 0, stream>>>(qkv_w, proj_w, Wq, Wp);
    qkv_gemm<<<dim3(12, 392), 256, 0, stream>>>(x, Wq, qkv_b, QKV);
    attn_mfma<<<4096, 256, 0, stream>>>(QKV, mask, rpb, AT);
    proj_gemm<<<dim3(4, 392), 256, 0, stream>>>(AT, Wp, proj_b, out);
}